// Round 1
// baseline (4329.729 us; speedup 1.0000x reference)
//
#include <hip/hip_runtime.h>

#define D      128
#define NINIT  100000
#define LVLS   64
#define M      4096
#define NRULES 256
#define NTOT   (NINIT + LVLS * M)

// ---------------------------------------------------------------------------
// store[node][128] fp32 lives in d_ws (offset 256 B). ws[0..1] = {sum_pos, sum_neg}.
// ---------------------------------------------------------------------------

__global__ __launch_bounds__(256) void init_kernel(
    const float* __restrict__ thax_table, const float* __restrict__ sine_table,
    const int* __restrict__ init_thax, const int* __restrict__ init_sine,
    float* __restrict__ store) {
  int idx = blockIdx.x * 256 + threadIdx.x;  // one float4 per thread
  int node = idx >> 5;
  int c = idx & 31;
  if (node >= NINIT) return;
  const float4* t = (const float4*)(thax_table + (size_t)init_thax[node] * D);
  const float4* s = (const float4*)(sine_table + (size_t)init_sine[node] * D);
  float4 a = t[c], b = s[c];
  float4 r = make_float4(a.x + b.x, a.y + b.y, a.z + b.z, a.w + b.w);
  ((float4*)(store + (size_t)node * D))[c] = r;
}

__global__ __launch_bounds__(256) void sum_kernel(
    const float* __restrict__ pos, const float* __restrict__ neg,
    float* __restrict__ sums) {
  float sp = 0.f, sn = 0.f;
  for (int i = blockIdx.x * 256 + threadIdx.x; i < NTOT; i += gridDim.x * 256) {
    sp += pos[i];
    sn += neg[i];
  }
  for (int m = 32; m; m >>= 1) {
    sp += __shfl_xor(sp, m, 64);
    sn += __shfl_xor(sn, m, 64);
  }
  if ((threadIdx.x & 63) == 0) {
    atomicAdd(&sums[0], sp);
    atomicAdd(&sums[1], sn);
  }
}

// One block per rule. Compact node list, then 16-node tiles:
// stage pe[16][256] in LDS, outer-product with streamed (prefetched) weights.
__global__ __launch_bounds__(256) void level_kernel(
    float* __restrict__ store, const int* __restrict__ parents,
    const int* __restrict__ rules, const float* __restrict__ W,
    const float* __restrict__ Bv, int n_base) {
  __shared__ int s_idx[M];
  __shared__ int s_cnt;
  __shared__ float4 s_pe[16][64];  // [node][k/4] : 256 floats = parent0|parent1

  const int r = blockIdx.x;
  if (threadIdx.x == 0) s_cnt = 0;
  __syncthreads();
  for (int i = threadIdx.x; i < M; i += 256)
    if (rules[i] == r) s_idx[atomicAdd(&s_cnt, 1)] = i;
  __syncthreads();
  const int cnt = s_cnt;

  const int o = threadIdx.x & 127;  // output column
  const int g = threadIdx.x >> 7;   // node-group (0: nodes 0-7, 1: nodes 8-15)
  const float* Wr = W + (size_t)r * (2 * D * D);
  const float bias = Bv[r * D + o];

  for (int t0 = 0; t0 < cnt; t0 += 16) {
    const int tile_n = min(16, cnt - t0);
    __syncthreads();  // previous tile's compute done before restaging
    // stage: 1024 float4 loads, coalesced 512B runs per parent row
    for (int q = threadIdx.x; q < 1024; q += 256) {
      int j = q >> 6, k4 = q & 63;
      int node = s_idx[t0 + ((j < tile_n) ? j : 0)];
      int par = parents[node * 2 + (k4 >> 5)];
      s_pe[j][k4] = ((const float4*)(store + (size_t)par * D))[k4 & 31];
    }
    __syncthreads();

    float acc[8];
#pragma unroll
    for (int j = 0; j < 8; ++j) acc[j] = 0.f;

    float w0 = Wr[0 * D + o], w1 = Wr[1 * D + o];
    float w2 = Wr[2 * D + o], w3 = Wr[3 * D + o];
    for (int k = 0; k < 256; k += 4) {
      float n0 = 0.f, n1 = 0.f, n2 = 0.f, n3 = 0.f;
      if (k < 252) {  // depth-1 prefetch of next 4 weight rows
        n0 = Wr[(k + 4) * D + o];
        n1 = Wr[(k + 5) * D + o];
        n2 = Wr[(k + 6) * D + o];
        n3 = Wr[(k + 7) * D + o];
      }
#pragma unroll
      for (int j = 0; j < 8; ++j) {
        float4 p = s_pe[g * 8 + j][k >> 2];
        acc[j] = fmaf(p.w, w3, fmaf(p.z, w2, fmaf(p.y, w1, fmaf(p.x, w0, acc[j]))));
      }
      w0 = n0; w1 = n1; w2 = n2; w3 = n3;
    }

#pragma unroll
    for (int j = 0; j < 8; ++j) {
      int jj = g * 8 + j;
      if (jj < tile_n) {
        int node = s_idx[t0 + jj];
        float v = acc[j] + bias;
        store[(size_t)(n_base + node) * D + o] = v > 0.f ? v : 0.f;
      }
    }
  }
}

__device__ __forceinline__ float softplusf(float x) {
  return fmaxf(x, 0.f) + log1pf(expf(-fabsf(x)));
}

// half-wave (32 lanes) per node: coalesced 512B row reads, shfl reduce.
__global__ __launch_bounds__(256) void loss_kernel(
    const float* __restrict__ store, const float* __restrict__ eval_w,
    const float* __restrict__ eval_b, const float* __restrict__ pos,
    const float* __restrict__ neg, const float* __restrict__ sums,
    float* __restrict__ out) {
  const int lane = threadIdx.x & 63;
  const int wave = threadIdx.x >> 6;
  const int node = (blockIdx.x * 4 + wave) * 2 + (lane >> 5);
  const int e = lane & 31;

  float dot = 0.f;
  if (node < NTOT) {
    float4 v = ((const float4*)(store + (size_t)node * D))[e];
    float4 w = ((const float4*)eval_w)[e];
    dot = v.x * w.x + v.y * w.y + v.z * w.z + v.w * w.w;
  }
  for (int m = 16; m; m >>= 1) dot += __shfl_xor(dot, m, 64);

  float l_loss = 0.f, l_pos = 0.f, l_neg = 0.f;
  if (e == 0 && node < NTOT) {
    float logit = dot + eval_b[0];
    float p = pos[node], n = neg[node];
    float tot = p + n;
    float y = p / tot;
    float pw = sums[1] / sums[0];
    l_loss = tot * (pw * y * softplusf(-logit) + (1.f - y) * softplusf(logit));
    if (logit >= 0.f) l_pos = p; else l_neg = n;
  }

  __shared__ float acc[3];
  if (threadIdx.x == 0) { acc[0] = 0.f; acc[1] = 0.f; acc[2] = 0.f; }
  __syncthreads();
  if (e == 0 && node < NTOT) {
    atomicAdd(&acc[0], l_loss);
    atomicAdd(&acc[1], l_pos);
    atomicAdd(&acc[2], l_neg);
  }
  __syncthreads();
  if (threadIdx.x == 0) {
    atomicAdd(&out[0], acc[0]);
    atomicAdd(&out[1], acc[1]);
    atomicAdd(&out[2], acc[2]);
  }
}

extern "C" void kernel_launch(void* const* d_in, const int* in_sizes, int n_in,
                              void* d_out, int out_size, void* d_ws, size_t ws_size,
                              hipStream_t stream) {
  const float* thax_table = (const float*)d_in[0];
  const float* sine_table = (const float*)d_in[1];
  const float* rule_W     = (const float*)d_in[2];
  const float* rule_b     = (const float*)d_in[3];
  const float* eval_w     = (const float*)d_in[4];
  const float* eval_b     = (const float*)d_in[5];
  const float* pos_vals   = (const float*)d_in[6];
  const float* neg_vals   = (const float*)d_in[7];
  const int*   init_thax  = (const int*)d_in[8];
  const int*   init_sine  = (const int*)d_in[9];
  const int*   parents    = (const int*)d_in[10];
  const int*   rules      = (const int*)d_in[11];

  float* out   = (float*)d_out;
  float* sums  = (float*)d_ws;
  float* store = (float*)((char*)d_ws + 256);

  hipMemsetAsync(d_out, 0, 3 * sizeof(float), stream);
  hipMemsetAsync(d_ws, 0, 2 * sizeof(float), stream);

  init_kernel<<<(NINIT * 32 + 255) / 256, 256, 0, stream>>>(
      thax_table, sine_table, init_thax, init_sine, store);
  sum_kernel<<<256, 256, 0, stream>>>(pos_vals, neg_vals, sums);

  for (int l = 0; l < LVLS; ++l) {
    level_kernel<<<NRULES, 256, 0, stream>>>(
        store, parents + (size_t)l * M * 2, rules + (size_t)l * M,
        rule_W, rule_b, NINIT + l * M);
  }

  loss_kernel<<<(NTOT + 7) / 8, 256, 0, stream>>>(
      store, eval_w, eval_b, pos_vals, neg_vals, sums, out);
}

// Round 2
// 2036.768 us; speedup vs baseline: 2.1258x; 2.1258x over previous
//
#include <hip/hip_runtime.h>

#define D      128
#define NINIT  100000
#define LVLS   64
#define M      4096
#define NRULES 256
#define NTOT   (NINIT + LVLS * M)
#define MAXC   256   // max nodes per (rule, level); Poisson(mean 16), 256 is unreachable

// ws layout: [0..8B) sums{pos,neg}; store[NTOT][128] fp32 at +256B.

__global__ __launch_bounds__(256) void init_kernel(
    const float* __restrict__ thax_table, const float* __restrict__ sine_table,
    const int* __restrict__ init_thax, const int* __restrict__ init_sine,
    float* __restrict__ store) {
  int idx = blockIdx.x * 256 + threadIdx.x;  // one float4 per thread
  int node = idx >> 5;
  int c = idx & 31;
  if (node >= NINIT) return;
  const float4* t = (const float4*)(thax_table + (size_t)init_thax[node] * D);
  const float4* s = (const float4*)(sine_table + (size_t)init_sine[node] * D);
  float4 a = t[c], b = s[c];
  ((float4*)(store + (size_t)node * D))[c] =
      make_float4(a.x + b.x, a.y + b.y, a.z + b.z, a.w + b.w);
}

__global__ __launch_bounds__(256) void sum_kernel(
    const float* __restrict__ pos, const float* __restrict__ neg,
    float* __restrict__ sums) {
  float sp = 0.f, sn = 0.f;
  for (int i = blockIdx.x * 256 + threadIdx.x; i < NTOT; i += gridDim.x * 256) {
    sp += pos[i];
    sn += neg[i];
  }
  for (int m = 32; m; m >>= 1) {
    sp += __shfl_xor(sp, m, 64);
    sn += __shfl_xor(sn, m, 64);
  }
  if ((threadIdx.x & 63) == 0) {
    atomicAdd(&sums[0], sp);
    atomicAdd(&sums[1], sn);
  }
}

// One block per rule, 512 threads = 128 cols x 4 node-groups.
// Thread: 1 output column, 4 nodes (acc[4]). LDS pe-tile reads are
// wave-uniform -> broadcast (cheap). Weight stream is coalesced + L2-resident.
__global__ __launch_bounds__(512) void level_kernel(
    float* __restrict__ store, const int* __restrict__ parents,
    const int* __restrict__ rules, const float* __restrict__ W,
    const float* __restrict__ Bv, int n_base) {
  __shared__ int s_idx[MAXC];
  __shared__ int s_cnt;
  __shared__ float4 s_pe[16][64];  // [node][k/4]: 256 floats = parent0|parent1

  const int r = blockIdx.x;
  if (threadIdx.x == 0) s_cnt = 0;
  __syncthreads();
  for (int i = threadIdx.x; i < M; i += 512)
    if (rules[i] == r) {
      int p = atomicAdd(&s_cnt, 1);
      if (p < MAXC) s_idx[p] = i;
    }
  __syncthreads();
  const int cnt = min(s_cnt, MAXC);

  const int col = threadIdx.x & 127;  // output column
  const int grp = threadIdx.x >> 7;   // node group: nodes grp*4 .. grp*4+3
  const float* Wr = W + (size_t)r * (2 * D * D);
  const float bias = Bv[r * D + col];

  for (int t0 = 0; t0 < cnt; t0 += 16) {
    const int tile_n = min(16, cnt - t0);
    __syncthreads();  // previous tile's compute done before restaging
    for (int q = threadIdx.x; q < 1024; q += 512) {
      int j = q >> 6, k4 = q & 63;
      int node = s_idx[t0 + ((j < tile_n) ? j : 0)];
      int par = parents[node * 2 + (k4 >> 5)];
      s_pe[j][k4] = ((const float4*)(store + (size_t)par * D))[k4 & 31];
    }
    __syncthreads();

    float acc[4] = {0.f, 0.f, 0.f, 0.f};
    float w0 = Wr[0 * D + col], w1 = Wr[1 * D + col];
    float w2 = Wr[2 * D + col], w3 = Wr[3 * D + col];
    for (int k = 0; k < 256; k += 4) {
      float n0 = 0.f, n1 = 0.f, n2 = 0.f, n3 = 0.f;
      if (k < 252) {  // depth-1 prefetch of next 4 weight rows
        n0 = Wr[(k + 4) * D + col];
        n1 = Wr[(k + 5) * D + col];
        n2 = Wr[(k + 6) * D + col];
        n3 = Wr[(k + 7) * D + col];
      }
#pragma unroll
      for (int j = 0; j < 4; ++j) {
        float4 p = s_pe[grp * 4 + j][k >> 2];
        acc[j] = fmaf(p.w, w3, fmaf(p.z, w2, fmaf(p.y, w1, fmaf(p.x, w0, acc[j]))));
      }
      w0 = n0; w1 = n1; w2 = n2; w3 = n3;
    }

#pragma unroll
    for (int j = 0; j < 4; ++j) {
      int jj = grp * 4 + j;
      if (jj < tile_n) {
        int node = s_idx[t0 + jj];
        float v = acc[j] + bias;
        store[(size_t)(n_base + node) * D + col] = v > 0.f ? v : 0.f;
      }
    }
  }
}

__device__ __forceinline__ float softplusf(float x) {
  return fmaxf(x, 0.f) + log1pf(expf(-fabsf(x)));
}

// Thread-per-node: wave reads 64 consecutive 512B rows (fully coalesced lines),
// 64 independent float4 loads in flight. One reduce + 3 atomics per block.
__global__ __launch_bounds__(1024) void loss_kernel(
    const float* __restrict__ store, const float* __restrict__ eval_w,
    const float* __restrict__ eval_b, const float* __restrict__ pos,
    const float* __restrict__ neg, const float* __restrict__ sums,
    float* __restrict__ out) {
  float a_loss = 0.f, a_pos = 0.f, a_neg = 0.f;
  const float pw = sums[1] / sums[0];
  const float eb = eval_b[0];
  const float4* wv = (const float4*)eval_w;

  for (int node = blockIdx.x * 1024 + threadIdx.x; node < NTOT;
       node += gridDim.x * 1024) {
    const float4* v = (const float4*)(store + (size_t)node * D);
    float dot = 0.f;
#pragma unroll
    for (int k = 0; k < 32; ++k) {
      float4 a = v[k], b = wv[k];
      dot += a.x * b.x + a.y * b.y + a.z * b.z + a.w * b.w;
    }
    float logit = dot + eb;
    float p = pos[node], n = neg[node];
    float tot = p + n, y = p / tot;
    a_loss += tot * (pw * y * softplusf(-logit) + (1.f - y) * softplusf(logit));
    if (logit >= 0.f) a_pos += p; else a_neg += n;
  }

  for (int m = 32; m; m >>= 1) {
    a_loss += __shfl_xor(a_loss, m, 64);
    a_pos  += __shfl_xor(a_pos,  m, 64);
    a_neg  += __shfl_xor(a_neg,  m, 64);
  }
  __shared__ float racc[3];
  if (threadIdx.x == 0) { racc[0] = 0.f; racc[1] = 0.f; racc[2] = 0.f; }
  __syncthreads();
  if ((threadIdx.x & 63) == 0) {
    atomicAdd(&racc[0], a_loss);
    atomicAdd(&racc[1], a_pos);
    atomicAdd(&racc[2], a_neg);
  }
  __syncthreads();
  if (threadIdx.x == 0) {
    atomicAdd(&out[0], racc[0]);
    atomicAdd(&out[1], racc[1]);
    atomicAdd(&out[2], racc[2]);
  }
}

extern "C" void kernel_launch(void* const* d_in, const int* in_sizes, int n_in,
                              void* d_out, int out_size, void* d_ws, size_t ws_size,
                              hipStream_t stream) {
  const float* thax_table = (const float*)d_in[0];
  const float* sine_table = (const float*)d_in[1];
  const float* rule_W     = (const float*)d_in[2];
  const float* rule_b     = (const float*)d_in[3];
  const float* eval_w     = (const float*)d_in[4];
  const float* eval_b     = (const float*)d_in[5];
  const float* pos_vals   = (const float*)d_in[6];
  const float* neg_vals   = (const float*)d_in[7];
  const int*   init_thax  = (const int*)d_in[8];
  const int*   init_sine  = (const int*)d_in[9];
  const int*   parents    = (const int*)d_in[10];
  const int*   rules      = (const int*)d_in[11];

  float* out   = (float*)d_out;
  float* sums  = (float*)d_ws;
  float* store = (float*)((char*)d_ws + 256);

  hipMemsetAsync(d_out, 0, 3 * sizeof(float), stream);
  hipMemsetAsync(d_ws, 0, 2 * sizeof(float), stream);

  init_kernel<<<(NINIT * 32 + 255) / 256, 256, 0, stream>>>(
      thax_table, sine_table, init_thax, init_sine, store);
  sum_kernel<<<256, 256, 0, stream>>>(pos_vals, neg_vals, sums);

  for (int l = 0; l < LVLS; ++l) {
    level_kernel<<<NRULES, 512, 0, stream>>>(
        store, parents + (size_t)l * M * 2, rules + (size_t)l * M,
        rule_W, rule_b, NINIT + l * M);
  }

  loss_kernel<<<256, 1024, 0, stream>>>(
      store, eval_w, eval_b, pos_vals, neg_vals, sums, out);
}

// Round 3
// 598.364 us; speedup vs baseline: 7.2359x; 3.4039x over previous
//
#include <hip/hip_runtime.h>

#define D      128
#define NINIT  100000
#define LVLS   64
#define M      4096
#define NRULES 256
#define NTOT   (NINIT + LVLS * M)

typedef __attribute__((ext_vector_type(8))) short short8;   // 8 bf16 = 4 VGPRs
typedef __attribute__((ext_vector_type(4))) float floatx4;  // MFMA accumulator

union U16x8 { uint4 u; short8 s; };

__device__ __forceinline__ unsigned short f2bf(float x) {  // RNE fp32->bf16
  unsigned u = __float_as_uint(x);
  u += 0x7fffu + ((u >> 16) & 1u);
  return (unsigned short)(u >> 16);
}
__device__ __forceinline__ float bf2f(unsigned short h) {
  return __uint_as_float(((unsigned)h) << 16);
}

// ---------------------------------------------------------------------------
// ws layout (bytes):
//   0        : sums[2] fp32
//   256      : store  bf16 [NTOT][128]            (92,708,864 B)
//   WF_OFF   : Wfrag  bf16 [NRULES][32768]  frag-linear (16,777,216 B)
//   SI_OFF   : sorted_idx int [LVLS][M]            (1,048,576 B)
//   RO_OFF   : rule_off  int [LVLS][NRULES+1]
// ---------------------------------------------------------------------------
#define ST_OFF 256
#define WF_OFF (ST_OFF + (size_t)NTOT * D * 2)
#define SI_OFF (WF_OFF + (size_t)NRULES * 2 * D * D * 2)
#define RO_OFF (SI_OFF + (size_t)LVLS * M * 4)

// One-time: rule_W fp32 [256][256][128] -> frag-linear bf16.
// Frag element (ks, ct, lane, j) = W[ks*32 + (lane>>4)*8 + j][ct*16 + (lane&15)]
// stored at Wfrag[r][((ks*8+ct)*64 + lane)*8 + j].  Writes: coalesced uint4.
__global__ __launch_bounds__(256) void wprep_kernel(
    const float* __restrict__ W, unsigned short* __restrict__ Wfrag) {
  const int r = blockIdx.x;
  const int wave = threadIdx.x >> 6, lane = threadIdx.x & 63;
  const float* Wr = W + (size_t)r * (2 * D * D);
  unsigned short* out = Wfrag + (size_t)r * (2 * D * D);
  for (int f = wave; f < 64; f += 4) {
    int ks = f >> 3, ct = f & 7;
    int krow = ks * 32 + (lane >> 4) * 8;
    int col = ct * 16 + (lane & 15);
    unsigned short v[8];
#pragma unroll
    for (int j = 0; j < 8; ++j) v[j] = f2bf(Wr[(size_t)(krow + j) * D + col]);
    uint4 pk;
    pk.x = (unsigned)v[0] | ((unsigned)v[1] << 16);
    pk.y = (unsigned)v[2] | ((unsigned)v[3] << 16);
    pk.z = (unsigned)v[4] | ((unsigned)v[5] << 16);
    pk.w = (unsigned)v[6] | ((unsigned)v[7] << 16);
    *(uint4*)(out + ((size_t)f * 64 + lane) * 8) = pk;
  }
}

// One-time: counting-sort nodes by rule, per level.
__global__ __launch_bounds__(256) void sort_kernel(
    const int* __restrict__ rules, int* __restrict__ sorted_idx,
    int* __restrict__ rule_off) {
  __shared__ int cnt[NRULES];
  __shared__ int base[NRULES + 1];
  const int l = blockIdx.x, t = threadIdx.x;
  const int* rl = rules + (size_t)l * M;
  cnt[t] = 0;
  __syncthreads();
  for (int m = t; m < M; m += 256) atomicAdd(&cnt[rl[m]], 1);
  __syncthreads();
  if (t == 0) {
    int run = 0;
    for (int r = 0; r < NRULES; ++r) { base[r] = run; run += cnt[r]; }
    base[NRULES] = run;
  }
  __syncthreads();
  rule_off[(size_t)l * (NRULES + 1) + t] = base[t];
  if (t == 0) rule_off[(size_t)l * (NRULES + 1) + NRULES] = base[NRULES];
  cnt[t] = base[t];
  __syncthreads();
  for (int m = t; m < M; m += 256) {
    int p = atomicAdd(&cnt[rl[m]], 1);
    sorted_idx[(size_t)l * M + p] = m;
  }
}

__global__ __launch_bounds__(256) void init_kernel(
    const float* __restrict__ thax_table, const float* __restrict__ sine_table,
    const int* __restrict__ init_thax, const int* __restrict__ init_sine,
    unsigned short* __restrict__ store) {
  int idx = blockIdx.x * 256 + threadIdx.x;  // (node, 8-elem segment)
  int node = idx >> 4, seg = idx & 15;
  if (node >= NINIT) return;
  const float4* t = (const float4*)(thax_table + (size_t)init_thax[node] * D) + seg * 2;
  const float4* s = (const float4*)(sine_table + (size_t)init_sine[node] * D) + seg * 2;
  float4 a0 = t[0], a1 = t[1], b0 = s[0], b1 = s[1];
  float v[8] = {a0.x + b0.x, a0.y + b0.y, a0.z + b0.z, a0.w + b0.w,
                a1.x + b1.x, a1.y + b1.y, a1.z + b1.z, a1.w + b1.w};
  uint4 pk;
  pk.x = (unsigned)f2bf(v[0]) | ((unsigned)f2bf(v[1]) << 16);
  pk.y = (unsigned)f2bf(v[2]) | ((unsigned)f2bf(v[3]) << 16);
  pk.z = (unsigned)f2bf(v[4]) | ((unsigned)f2bf(v[5]) << 16);
  pk.w = (unsigned)f2bf(v[6]) | ((unsigned)f2bf(v[7]) << 16);
  *(uint4*)(store + (size_t)node * D + seg * 8) = pk;
}

__global__ __launch_bounds__(256) void sum_kernel(
    const float* __restrict__ pos, const float* __restrict__ neg,
    float* __restrict__ sums) {
  float sp = 0.f, sn = 0.f;
  for (int i = blockIdx.x * 256 + threadIdx.x; i < NTOT; i += gridDim.x * 256) {
    sp += pos[i];
    sn += neg[i];
  }
  for (int m = 32; m; m >>= 1) {
    sp += __shfl_xor(sp, m, 64);
    sn += __shfl_xor(sn, m, 64);
  }
  if ((threadIdx.x & 63) == 0) {
    atomicAdd(&sums[0], sp);
    atomicAdd(&sums[1], sn);
  }
}

// One block per rule, 512 thr = 8 waves; wave w owns output cols [16w,16w+16).
// B-frags (weights) loaded ONCE into 32 VGPRs, reused across tiles.
// Per 16-node tile: stage pe (16x256 bf16, padded rows) in LDS, 8 ds_read_b128
// + 8 MFMA per wave, write C (ReLU+bias) to bf16 store.
__global__ __launch_bounds__(512) void level_kernel(
    unsigned short* __restrict__ store, const int* __restrict__ parents,
    const int* __restrict__ sorted_idx_l, const int* __restrict__ rule_off_l,
    const unsigned short* __restrict__ Wfrag, const float* __restrict__ Bv,
    int n_base) {
  __shared__ unsigned short pe[16 * 264];  // 528B rows: 256 data + 8 bf16 pad

  const int r = blockIdx.x;
  const int off0 = rule_off_l[r];
  const int cnt = rule_off_l[r + 1] - off0;
  if (cnt == 0) return;

  const int tid = threadIdx.x;
  const int wave = tid >> 6, lane = tid & 63;
  const int col = (wave << 4) + (lane & 15);
  const float bias = Bv[r * D + col];
  const unsigned short* wf = Wfrag + (size_t)r * (2 * D * D);

  short8 bf[8];
#pragma unroll
  for (int ks = 0; ks < 8; ++ks) {
    U16x8 c;
    c.u = *(const uint4*)(wf + (((size_t)ks * 8 + wave) * 64 + lane) * 8);
    bf[ks] = c.s;
  }

  const int snode = tid >> 5, seg = tid & 31;  // staging role: 1 uint4/thread

  for (int t0 = 0; t0 < cnt; t0 += 16) {
    __syncthreads();  // previous tile's reads done before restage
    {
      int gj = t0 + snode;
      if (gj > cnt - 1) gj = cnt - 1;
      int sid = sorted_idx_l[off0 + gj];
      int par = parents[sid * 2 + (seg >> 4)];
      uint4 d = *(const uint4*)(store + (size_t)par * D + (seg & 15) * 8);
      *(uint4*)(pe + snode * 264 + seg * 8) = d;
    }
    __syncthreads();

    floatx4 acc = {0.f, 0.f, 0.f, 0.f};
#pragma unroll
    for (int ks = 0; ks < 8; ++ks) {
      short8 a = *(const short8*)(pe + (lane & 15) * 264 + ks * 32 + (lane >> 4) * 8);
      acc = __builtin_amdgcn_mfma_f32_16x16x32_bf16(a, bf[ks], acc, 0, 0, 0);
    }

#pragma unroll
    for (int reg = 0; reg < 4; ++reg) {
      int row = (lane >> 4) * 4 + reg;
      int gj = t0 + row;
      if (gj < cnt) {
        int sid = sorted_idx_l[off0 + gj];
        float v = acc[reg] + bias;
        store[(size_t)(n_base + sid) * D + col] = f2bf(v > 0.f ? v : 0.f);
      }
    }
  }
}

__device__ __forceinline__ float softplusf(float x) {
  return fmaxf(x, 0.f) + log1pf(expf(-fabsf(x)));
}

__global__ __launch_bounds__(1024) void loss_kernel(
    const unsigned short* __restrict__ store, const float* __restrict__ eval_w,
    const float* __restrict__ eval_b, const float* __restrict__ pos,
    const float* __restrict__ neg, const float* __restrict__ sums,
    float* __restrict__ out) {
  float a_loss = 0.f, a_pos = 0.f, a_neg = 0.f;
  const float pw = sums[1] / sums[0];
  const float eb = eval_b[0];
  const float4* wv = (const float4*)eval_w;

  for (int node = blockIdx.x * 1024 + threadIdx.x; node < NTOT;
       node += gridDim.x * 1024) {
    const uint4* v = (const uint4*)(store + (size_t)node * D);
    float dot = 0.f;
#pragma unroll
    for (int k = 0; k < 16; ++k) {
      uint4 u = v[k];
      float4 w0 = wv[k * 2], w1 = wv[k * 2 + 1];
      dot += __uint_as_float(u.x << 16) * w0.x +
             __uint_as_float(u.x & 0xffff0000u) * w0.y +
             __uint_as_float(u.y << 16) * w0.z +
             __uint_as_float(u.y & 0xffff0000u) * w0.w +
             __uint_as_float(u.z << 16) * w1.x +
             __uint_as_float(u.z & 0xffff0000u) * w1.y +
             __uint_as_float(u.w << 16) * w1.z +
             __uint_as_float(u.w & 0xffff0000u) * w1.w;
    }
    float logit = dot + eb;
    float p = pos[node], n = neg[node];
    float tot = p + n, y = p / tot;
    a_loss += tot * (pw * y * softplusf(-logit) + (1.f - y) * softplusf(logit));
    if (logit >= 0.f) a_pos += p; else a_neg += n;
  }

  for (int m = 32; m; m >>= 1) {
    a_loss += __shfl_xor(a_loss, m, 64);
    a_pos  += __shfl_xor(a_pos,  m, 64);
    a_neg  += __shfl_xor(a_neg,  m, 64);
  }
  __shared__ float racc[3];
  if (threadIdx.x == 0) { racc[0] = 0.f; racc[1] = 0.f; racc[2] = 0.f; }
  __syncthreads();
  if ((threadIdx.x & 63) == 0) {
    atomicAdd(&racc[0], a_loss);
    atomicAdd(&racc[1], a_pos);
    atomicAdd(&racc[2], a_neg);
  }
  __syncthreads();
  if (threadIdx.x == 0) {
    atomicAdd(&out[0], racc[0]);
    atomicAdd(&out[1], racc[1]);
    atomicAdd(&out[2], racc[2]);
  }
}

extern "C" void kernel_launch(void* const* d_in, const int* in_sizes, int n_in,
                              void* d_out, int out_size, void* d_ws, size_t ws_size,
                              hipStream_t stream) {
  const float* thax_table = (const float*)d_in[0];
  const float* sine_table = (const float*)d_in[1];
  const float* rule_W     = (const float*)d_in[2];
  const float* rule_b     = (const float*)d_in[3];
  const float* eval_w     = (const float*)d_in[4];
  const float* eval_b     = (const float*)d_in[5];
  const float* pos_vals   = (const float*)d_in[6];
  const float* neg_vals   = (const float*)d_in[7];
  const int*   init_thax  = (const int*)d_in[8];
  const int*   init_sine  = (const int*)d_in[9];
  const int*   parents    = (const int*)d_in[10];
  const int*   rules      = (const int*)d_in[11];

  float* out = (float*)d_out;
  char* ws = (char*)d_ws;
  float* sums = (float*)ws;
  unsigned short* store = (unsigned short*)(ws + ST_OFF);
  unsigned short* Wfrag = (unsigned short*)(ws + WF_OFF);
  int* sorted_idx = (int*)(ws + SI_OFF);
  int* rule_off   = (int*)(ws + RO_OFF);

  hipMemsetAsync(d_out, 0, 3 * sizeof(float), stream);
  hipMemsetAsync(d_ws, 0, 2 * sizeof(float), stream);

  wprep_kernel<<<NRULES, 256, 0, stream>>>(rule_W, Wfrag);
  sort_kernel<<<LVLS, 256, 0, stream>>>(rules, sorted_idx, rule_off);
  init_kernel<<<(NINIT * 16 + 255) / 256, 256, 0, stream>>>(
      thax_table, sine_table, init_thax, init_sine, store);
  sum_kernel<<<256, 256, 0, stream>>>(pos_vals, neg_vals, sums);

  for (int l = 0; l < LVLS; ++l) {
    level_kernel<<<NRULES, 512, 0, stream>>>(
        store, parents + (size_t)l * M * 2,
        sorted_idx + (size_t)l * M, rule_off + (size_t)l * (NRULES + 1),
        Wfrag, rule_b, NINIT + l * M);
  }

  loss_kernel<<<256, 1024, 0, stream>>>(
      store, eval_w, eval_b, pos_vals, neg_vals, sums, out);
}